// Round 1
// baseline (1067.414 us; speedup 1.0000x reference)
//
#include <hip/hip_runtime.h>
#include <math.h>

#define S_LEN    4096
#define D_DIM    128
#define R_TOP    16
#define K_SEL    256
#define NTHREADS 512
#define NWAVES   (NTHREADS / 64)

__device__ __forceinline__ unsigned f2key(float f) {
    unsigned u = __float_as_uint(f);
    return (u & 0x80000000u) ? ~u : (u | 0x80000000u);
}

__device__ __forceinline__ float blockReduceSum(float v, float* s_red, int tid) {
#pragma unroll
    for (int off = 32; off > 0; off >>= 1) v += __shfl_xor(v, off, 64);
    __syncthreads();
    if ((tid & 63) == 0) s_red[tid >> 6] = v;
    __syncthreads();
    float r = 0.f;
#pragma unroll
    for (int i = 0; i < NWAVES; ++i) r += s_red[i];
    return r;
}

__device__ __forceinline__ float blockReduceMax(float v, float* s_red, int tid) {
#pragma unroll
    for (int off = 32; off > 0; off >>= 1) v = fmaxf(v, __shfl_xor(v, off, 64));
    __syncthreads();
    if ((tid & 63) == 0) s_red[tid >> 6] = v;
    __syncthreads();
    float r = s_red[0];
#pragma unroll
    for (int i = 1; i < NWAVES; ++i) r = fmaxf(r, s_red[i]);
    return r;
}

__global__ __launch_bounds__(NTHREADS)
void sparq_fused_kernel(const float* __restrict__ Q,
                        const float* __restrict__ K,
                        const float* __restrict__ V,
                        float* __restrict__ Out)
{
    const int head = blockIdx.x;                     // 0..255 == (b*H + h)
    const size_t kv_base = (size_t)head * S_LEN * D_DIM;
    const float* __restrict__ Kh = K + kv_base;
    const float* __restrict__ Vh = V + kv_base;
    const float* __restrict__ Qh = Q + (size_t)head * D_DIM;

    __shared__ float  s_scores[S_LEN];               // 16 KB: QK_hat per position
    __shared__ float4 s_part4[16][32];               // 8 KB: partial reductions (y, V_mean)
    __shared__ float  s_q[D_DIM];
    __shared__ float  s_absq[D_DIM];
    __shared__ int    s_i1[R_TOP];
    __shared__ float  s_qhat[R_TOP];
    __shared__ unsigned s_hist[256];
    __shared__ int    s_sel[K_SEL];
    __shared__ float  s_w[K_SEL];
    __shared__ float  s_red[NWAVES];
    __shared__ float  s_bcast[4];
    __shared__ unsigned s_cnt[4];

    const int tid = threadIdx.x;

    // ---------- Stage 0: load Q, |Q|, sum_all ----------
    if (tid < D_DIM) {
        float qv = Qh[tid];
        s_q[tid] = qv;
        s_absq[tid] = fabsf(qv);
    }
    __syncthreads();

    float sum_all;
    {
        float v = (tid < D_DIM) ? s_absq[tid] : 0.f;
        sum_all = blockReduceSum(v, s_red, tid);
    }

    // ---------- Stage 0b: top-16 of |Q| (wave 0 argmax x16, tie -> lower idx) ----------
    float sumtop_t0 = 0.f;   // valid on tid==0
    for (int it = 0; it < R_TOP; ++it) {
        if (tid < 64) {
            float a = s_absq[tid];
            float b = s_absq[tid + 64];
            float v;  int idx;
            if (a >= b) { v = a; idx = tid; } else { v = b; idx = tid + 64; }
#pragma unroll
            for (int off = 32; off > 0; off >>= 1) {
                float ov = __shfl_xor(v, off, 64);
                int   oi = __shfl_xor(idx, off, 64);
                if (ov > v || (ov == v && oi < idx)) { v = ov; idx = oi; }
            }
            if (tid == 0) {
                s_i1[it]   = idx;
                s_qhat[it] = s_q[idx];
                s_absq[idx] = -1.0f;
                sumtop_t0 += v;
            }
        }
        __syncthreads();
    }
    if (tid == 0) {
        float scale = sqrtf((float)D_DIM * sumtop_t0 / sum_all);
        s_bcast[0] = 1.0f / scale;
    }
    __syncthreads();
    const float inv_scale = s_bcast[0];

    // ---------- Stage 1: QK_hat over all S (16-dim gather) ----------
    int   i1r[R_TOP];
    float qhr[R_TOP];
#pragma unroll
    for (int t = 0; t < R_TOP; ++t) { i1r[t] = s_i1[t]; qhr[t] = s_qhat[t]; }

    float lmax = -INFINITY;
    for (int s = tid; s < S_LEN; s += NTHREADS) {
        const float* __restrict__ row = Kh + (size_t)s * D_DIM;
        float acc = 0.f;
#pragma unroll
        for (int t = 0; t < R_TOP; ++t) acc += qhr[t] * row[i1r[t]];
        s_scores[s] = acc;
        lmax = fmaxf(lmax, acc);
    }
    const float m = blockReduceMax(lmax, s_red, tid);

    float lsum = 0.f;
    for (int s = tid; s < S_LEN; s += NTHREADS)
        lsum += __expf((s_scores[s] - m) * inv_scale);
    const float denom = blockReduceSum(lsum, s_red, tid);

    // ---------- Stage 2: exact top-256 via 4-pass radix select ----------
    unsigned prefix = 0, base_gt = 0;
    for (int pass = 0; pass < 4; ++pass) {
        const int shift = 24 - 8 * pass;
        if (tid < 256) s_hist[tid] = 0u;
        __syncthreads();
        for (int s = tid; s < S_LEN; s += NTHREADS) {
            unsigned key = f2key(s_scores[s]);
            bool in = (pass == 0) ? true : ((key >> (shift + 8)) == prefix);
            if (in) atomicAdd(&s_hist[(key >> shift) & 255u], 1u);
        }
        __syncthreads();
        if (tid == 0) {
            unsigned run = base_gt; unsigned b = 0;
            for (int bin = 255; bin >= 0; --bin) {
                unsigned c = s_hist[bin];
                if (run + c >= K_SEL) { b = (unsigned)bin; break; }
                run += c;
            }
            s_cnt[0] = run;
            s_cnt[1] = (prefix << 8) | b;
        }
        __syncthreads();
        base_gt = s_cnt[0];
        prefix  = s_cnt[1];
    }
    const unsigned T = prefix;
    const unsigned count_gt = base_gt;

    // compaction + alpha numerator
    if (tid == 0) { s_cnt[2] = 0u; s_cnt[3] = 0u; }
    __syncthreads();
    float alpha_part = 0.f;
    for (int s = tid; s < S_LEN; s += NTHREADS) {
        float sc = s_scores[s];
        unsigned key = f2key(sc);
        int slot = -1;
        if (key > T) {
            slot = (int)atomicAdd(&s_cnt[2], 1u);
        } else if (key == T) {
            unsigned p = atomicAdd(&s_cnt[3], 1u);
            if (count_gt + p < K_SEL) slot = (int)(count_gt + p);
        }
        if (slot >= 0) {
            s_sel[slot] = s;
            alpha_part += __expf((sc - m) * inv_scale);
        }
    }
    const float alpha = blockReduceSum(alpha_part, s_red, tid) / denom;

    // ---------- Stage 3: exact logits over 256 selected rows (2 threads/row) ----------
    {
        const int j    = tid >> 1;
        const int half = tid & 1;
        const int srow = s_sel[j];
        const float4* __restrict__ kr =
            (const float4*)(Kh + (size_t)srow * D_DIM) + half * 16;
        float acc = 0.f;
#pragma unroll
        for (int c = 0; c < 16; ++c) {
            float4 kv = kr[c];
            int d0 = half * 64 + c * 4;
            acc += s_q[d0] * kv.x + s_q[d0 + 1] * kv.y
                 + s_q[d0 + 2] * kv.z + s_q[d0 + 3] * kv.w;
        }
        acc += __shfl_xor(acc, 1, 64);
        if (half == 0) s_w[j] = acc * 0.08838834764831845f;  // 1/sqrt(128)
    }
    __syncthreads();

    // softmax over the 256 selected logits
    float lv = (tid < K_SEL) ? s_w[tid] : -INFINITY;
    const float m2 = blockReduceMax(lv, s_red, tid);
    float e = (tid < K_SEL) ? __expf(lv - m2) : 0.f;
    const float Wsum = blockReduceSum(e, s_red, tid);
    if (tid < K_SEL) s_w[tid] = e;
    const float recipW = 1.0f / Wsum;
    __syncthreads();

    // ---------- Stage 4: y = sum_j w_j * V[sel_j, :] ----------
    {
        const int g = tid >> 5;      // 0..15
        const int c = tid & 31;      // float4 column
        float4 acc = make_float4(0.f, 0.f, 0.f, 0.f);
        for (int j = g; j < K_SEL; j += 16) {
            const int srow = s_sel[j];
            const float w = s_w[j];
            float4 vv = ((const float4*)(Vh + (size_t)srow * D_DIM))[c];
            acc.x += w * vv.x; acc.y += w * vv.y;
            acc.z += w * vv.z; acc.w += w * vv.w;
        }
        s_part4[g][c] = acc;
    }
    __syncthreads();
    float yd = 0.f;
    if (tid < D_DIM) {
        const float* pf = (const float*)s_part4;
        for (int g = 0; g < 16; ++g) yd += pf[g * D_DIM + tid];
    }
    __syncthreads();   // protect s_part4 reuse

    // ---------- Stage 5: V_mean over all S (full coalesced stream) ----------
    {
        const int g = tid >> 5;      // 0..15
        const int c = tid & 31;
        float4 acc = make_float4(0.f, 0.f, 0.f, 0.f);
        const float4* __restrict__ v4 = (const float4*)Vh;
#pragma unroll 4
        for (int s = g; s < S_LEN; s += 16) {
            float4 vv = v4[(size_t)s * 32 + c];
            acc.x += vv.x; acc.y += vv.y; acc.z += vv.z; acc.w += vv.w;
        }
        s_part4[g][c] = acc;
    }
    __syncthreads();

    // ---------- Stage 6: combine & write ----------
    if (tid < D_DIM) {
        const float* pf = (const float*)s_part4;
        float vm = 0.f;
        for (int g = 0; g < 16; ++g) vm += pf[g * D_DIM + tid];
        vm *= (1.0f / (float)S_LEN);
        const float y = yd * recipW;
        Out[(size_t)head * D_DIM + tid] = vm + alpha * (y - vm);
    }
}

extern "C" void kernel_launch(void* const* d_in, const int* in_sizes, int n_in,
                              void* d_out, int out_size, void* d_ws, size_t ws_size,
                              hipStream_t stream) {
    const float* Q = (const float*)d_in[0];
    const float* K = (const float*)d_in[1];
    const float* V = (const float*)d_in[2];
    // d_in[3] = mask (all true), d_in[4] = r (16), d_in[5] = k (256) — constants per setup
    float* Out = (float*)d_out;
    sparq_fused_kernel<<<dim3(256), dim3(NTHREADS), 0, stream>>>(Q, K, V, Out);
}